// Round 1
// baseline (1241.100 us; speedup 1.0000x reference)
//
#include <hip/hip_runtime.h>

// FNO layer: rfftn -> fftshift -> crop(32x32x32 modes) -> einsum(boixy,iotxy->botxy)
// -> scatter -> fftshift -> irfftn.  Implemented as separable dense DFT stages
// (only 32 modes per axis are live) + memory-bound einsum.  All fp32.
//
// Mode maps (derived from numpy fftshift/roll semantics):
//   forward Y (rfft len 65):  block j -> bin fy(j) = (j-16) mod 65  (j<16: j+49, j>=16: j-16)
//   forward X (fft len 128):  block l -> freq (l-16)       phase e^{-2pi i (l-16) x/128}
//   forward T:                i in [0,32), phase e^{-2pi i i tau/64}
//   inverse T:                e^{+2pi i t tau/64} / (64*128*128)   (all norm folded here)
//   inverse X:                e^{+2pi i (l-16) Xp/128}
//   inverse Y (irfft):        block j lands at bin g(j) = (j+48) mod 65 (double fftshift on odd axis!)
//                             out += s_j*(Re*cos - Im*sin), s_j=2 except bins 0/64 (j=17/16): s=1, Im ignored.

#define PI_F 3.14159265358979323846f

// ---- ws layout (bytes) ----
static constexpr size_t OFF_TWFX  = 0;                    // [x=128][l=32] float2  32KB
static constexpr size_t OFF_TWFY  = 32768;                // [y=128][j=32] float2  32KB
static constexpr size_t OFF_TWFT  = 65536;                // [tau=64][i=32] float2 16KB
static constexpr size_t OFF_TWIT  = 81920;                // [tau=64][t=32] float2 16KB (incl 1/1048576)
static constexpr size_t OFF_TWIX  = 98304;                // [Xp=128][l=32] float2 32KB
static constexpr size_t OFF_TWIYR = 131072;               // [j=32][Yp=128] float  16KB
static constexpr size_t OFF_TWIYI = 147456;               // 16KB
static constexpr size_t OFF_A     = 163840;               // S1 (fwd-x out) / S6 (inv-x out): 134217728 B
static constexpr size_t OFF_C     = OFF_A;                // S3 (block)   : 16777216 B (A is dead then)
static constexpr size_t OFF_D     = OFF_A + 16777216ULL;  // S4 (einsum out): 16777216 B
static constexpr size_t OFF_B     = OFF_A + 134217728ULL; // S2 (fwd-y out) / S5 (inv-t out): 33554432 B
// total ws need: OFF_B + 33554432 = 167,936,000 bytes (~160.2 MiB)

__device__ __forceinline__ void cmadd(float2& a, float2 u, float2 v) {
  a.x = fmaf(u.x, v.x, fmaf(-u.y, v.y, a.x));
  a.y = fmaf(u.x, v.y, fmaf( u.y, v.x, a.y));
}

// ---------------- twiddle tables ----------------
__global__ void init_tables(char* __restrict__ ws) {
  int idx = blockIdx.x * 256 + threadIdx.x;
  if (idx >= 20480) return;
  float2* twFX  = (float2*)(ws + OFF_TWFX);
  float2* twFY  = (float2*)(ws + OFF_TWFY);
  float2* twFT  = (float2*)(ws + OFF_TWFT);
  float2* twIT  = (float2*)(ws + OFF_TWIT);
  float2* twIX  = (float2*)(ws + OFF_TWIX);
  float*  twIYr = (float*)(ws + OFF_TWIYR);
  float*  twIYi = (float*)(ws + OFF_TWIYI);

  if (idx < 4096) {                       // twFX [x][l]
    int x = idx >> 5, l = idx & 31;
    int r = (((l - 16) * x) % 128 + 128) % 128;
    float a = -2.0f * PI_F * (float)r / 128.0f;
    float s, c; sincosf(a, &s, &c);
    twFX[idx] = make_float2(c, s);
  } else if (idx < 8192) {                // twFY [y][j]
    int k = idx - 4096;
    int y = k >> 5, j = k & 31;
    int f = (j >= 16) ? (j - 16) : (j + 49);
    int r = (f * y) % 128;
    float a = -2.0f * PI_F * (float)r / 128.0f;
    float s, c; sincosf(a, &s, &c);
    twFY[k] = make_float2(c, s);
  } else if (idx < 10240) {               // twFT [tau][i]
    int k = idx - 8192;
    int tau = k >> 5, i = k & 31;
    int r = (i * tau) % 64;
    float a = -2.0f * PI_F * (float)r / 64.0f;
    float s, c; sincosf(a, &s, &c);
    twFT[k] = make_float2(c, s);
  } else if (idx < 12288) {               // twIT [tau][t], includes 1/(64*128*128)
    int k = idx - 10240;
    int tau = k >> 5, t = k & 31;
    int r = (t * tau) % 64;
    float a = 2.0f * PI_F * (float)r / 64.0f;
    float s, c; sincosf(a, &s, &c);
    const float n = 1.0f / 1048576.0f;
    twIT[k] = make_float2(c * n, s * n);
  } else if (idx < 16384) {               // twIX [Xp][l]
    int k = idx - 12288;
    int Xp = k >> 5, l = k & 31;
    int r = (((l - 16) * Xp) % 128 + 128) % 128;
    float a = 2.0f * PI_F * (float)r / 128.0f;
    float s, c; sincosf(a, &s, &c);
    twIX[k] = make_float2(c, s);
  } else {                                // twIY [j][Yp]
    int k = idx - 16384;
    int j = k >> 7, Yp = k & 127;
    int g = (j + 48) % 65;                // final rfft bin
    int r = (g * Yp) % 128;
    float a = 2.0f * PI_F * (float)r / 128.0f;
    float s, c; sincosf(a, &s, &c);
    bool edge = (j == 16) || (j == 17);   // Nyquist / DC: no doubling, Im ignored
    float sc = edge ? 1.0f : 2.0f;
    twIYr[k] = sc * c;
    twIYi[k] = edge ? 0.0f : (-sc * s);
  }
}

// ---------------- forward X: real x (slab 128x128) -> S1 [slab][l=32][y=128] ----------------
__global__ void __launch_bounds__(256) k_fwd_x(const float* __restrict__ x,
                                               float2* __restrict__ S1,
                                               const float2* __restrict__ twFX) {
  __shared__ float2 tw[4096];
  for (int i = threadIdx.x; i < 4096; i += 256) tw[i] = twFX[i];
  __syncthreads();
  int slab = blockIdx.x * 2 + (threadIdx.x >> 7);     // (b*32+c)*64+tau
  int y = threadIdx.x & 127;
  const float* xp = x + (size_t)slab * 16384;
  float2 acc[32];
#pragma unroll
  for (int l = 0; l < 32; ++l) acc[l] = make_float2(0.f, 0.f);
  for (int xx = 0; xx < 128; ++xx) {
    float v = xp[xx * 128 + y];
    const float2* twr = &tw[xx * 32];
#pragma unroll
    for (int l = 0; l < 32; ++l) {
      acc[l].x = fmaf(v, twr[l].x, acc[l].x);
      acc[l].y = fmaf(v, twr[l].y, acc[l].y);
    }
  }
  float2* outp = S1 + (size_t)slab * 4096;
#pragma unroll
  for (int l = 0; l < 32; ++l) outp[l * 128 + y] = acc[l];
}

// ---------------- forward Y: S1 rows (len-128 complex) -> S2 [row][j=32] ----------------
// 16 rows per block; thread = (rslot 0..7 -> 2 rows, j 0..31)
__global__ void __launch_bounds__(256) k_fwd_y(const float2* __restrict__ S1,
                                               float2* __restrict__ S2,
                                               const float2* __restrict__ twFY) {
  __shared__ float2 tw[4096];    // [y][j] 32KB
  __shared__ float2 rows[2048];  // 16 rows x 128  16KB
  for (int i = threadIdx.x; i < 4096; i += 256) tw[i] = twFY[i];
  const float2* src = S1 + (size_t)blockIdx.x * 2048;
  for (int i = threadIdx.x; i < 2048; i += 256) rows[i] = src[i];
  __syncthreads();
  int j = threadIdx.x & 31;
  int rslot = threadIdx.x >> 5;  // 0..7
  float2 acc[2];
  acc[0] = make_float2(0.f, 0.f);
  acc[1] = make_float2(0.f, 0.f);
  for (int y = 0; y < 128; ++y) {
    float2 t = tw[y * 32 + j];
#pragma unroll
    for (int k = 0; k < 2; ++k) {
      float2 e = rows[(rslot * 2 + k) * 128 + y];
      cmadd(acc[k], e, t);
    }
  }
  float2* dst = S2 + (size_t)blockIdx.x * 16 * 32;
#pragma unroll
  for (int k = 0; k < 2; ++k) dst[(rslot * 2 + k) * 32 + j] = acc[k];
}

// ---------------- forward T: S2 [bc][tau=64][site=1024] -> S3 [bc][i=32][site] ----------------
__global__ void __launch_bounds__(256) k_fwd_t(const float2* __restrict__ S2,
                                               float2* __restrict__ S3,
                                               const float2* __restrict__ twFT) {
  __shared__ float2 tw[2048];    // [tau][i]
  for (int i = threadIdx.x; i < 2048; i += 256) tw[i] = twFT[i];
  __syncthreads();
  int bc = blockIdx.x >> 3;
  int sg = (blockIdx.x >> 1) & 3;
  int ih = blockIdx.x & 1;
  int s = sg * 256 + threadIdx.x;
  const float2* in = S2 + (size_t)bc * 65536 + s;
  float2 acc[16];
#pragma unroll
  for (int q = 0; q < 16; ++q) acc[q] = make_float2(0.f, 0.f);
  for (int tau = 0; tau < 64; ++tau) {
    float2 v = in[(size_t)tau * 1024];
    const float2* twr = &tw[tau * 32 + ih * 16];
#pragma unroll
    for (int q = 0; q < 16; ++q) cmadd(acc[q], v, twr[q]);
  }
  float2* outp = S3 + (size_t)bc * 32768 + (size_t)(ih * 16) * 1024 + s;
#pragma unroll
  for (int q = 0; q < 16; ++q) outp[(size_t)q * 1024] = acc[q];
}

// ---------------- einsum: out[b,o,t,s] = sum_i block[b,o,i,s] * (wr+i wi)[i,o,t,s] ----------------
__global__ void __launch_bounds__(256, 2) k_einsum(const float2* __restrict__ S3,
                                                   const float* __restrict__ wr,
                                                   const float* __restrict__ wi,
                                                   float2* __restrict__ S4) {
  int o  = blockIdx.x >> 4;
  int tc = (blockIdx.x >> 2) & 3;
  int sg = blockIdx.x & 3;
  int s = sg * 256 + threadIdx.x;
  float2 blk0[32], blk1[32];
#pragma unroll
  for (int i = 0; i < 32; ++i) {
    blk0[i] = S3[(size_t)(o * 32 + i) * 1024 + s];
    blk1[i] = S3[(size_t)((32 + o) * 32 + i) * 1024 + s];
  }
  for (int tt = 0; tt < 8; ++tt) {
    int t = tc * 8 + tt;
    float2 a0 = make_float2(0.f, 0.f), a1 = make_float2(0.f, 0.f);
#pragma unroll
    for (int i = 0; i < 32; ++i) {
      size_t widx = (size_t)((i * 32 + o) * 32 + t) * 1024 + s;
      float r = wr[widx], m = wi[widx];
      a0.x = fmaf(blk0[i].x, r, fmaf(-blk0[i].y, m, a0.x));
      a0.y = fmaf(blk0[i].x, m, fmaf( blk0[i].y, r, a0.y));
      a1.x = fmaf(blk1[i].x, r, fmaf(-blk1[i].y, m, a1.x));
      a1.y = fmaf(blk1[i].x, m, fmaf( blk1[i].y, r, a1.y));
    }
    S4[(size_t)(o * 32 + t) * 1024 + s] = a0;
    S4[(size_t)((32 + o) * 32 + t) * 1024 + s] = a1;
  }
}

// ---------------- inverse T: S4 [bo][t=32][site] -> S5 [bo][tau=64][site] ----------------
__global__ void __launch_bounds__(256) k_inv_t(const float2* __restrict__ S4,
                                               float2* __restrict__ S5,
                                               const float2* __restrict__ twIT) {
  __shared__ float2 tw[2048];    // [tau][t]
  for (int i = threadIdx.x; i < 2048; i += 256) tw[i] = twIT[i];
  __syncthreads();
  int bo = blockIdx.x >> 3;
  int sg = (blockIdx.x >> 1) & 3;
  int th = blockIdx.x & 1;
  int s = sg * 256 + threadIdx.x;
  float2 in[32];
#pragma unroll
  for (int t = 0; t < 32; ++t) in[t] = S4[(size_t)bo * 32768 + (size_t)t * 1024 + s];
  for (int t2 = 0; t2 < 32; ++t2) {
    int tau = th * 32 + t2;
    float2 a = make_float2(0.f, 0.f);
    const float2* twr = &tw[tau * 32];
#pragma unroll
    for (int t = 0; t < 32; ++t) cmadd(a, in[t], twr[t]);
    S5[(size_t)bo * 65536 + (size_t)tau * 1024 + s] = a;
  }
}

// ---------------- inverse X: S5 slab [l=32][j=32] -> S6 [slab][Xp=128][j=32] ----------------
__global__ void __launch_bounds__(256) k_inv_x(const float2* __restrict__ S5,
                                               float2* __restrict__ S6,
                                               const float2* __restrict__ twIX) {
  __shared__ float2 tw[4096];    // [Xp][l] 32KB
  __shared__ float2 inb[1024];   // [l][j]  8KB
  for (int i = threadIdx.x; i < 4096; i += 256) tw[i] = twIX[i];
  const float2* src = S5 + (size_t)blockIdx.x * 1024;
  for (int i = threadIdx.x; i < 1024; i += 256) inb[i] = src[i];
  __syncthreads();
  int j  = threadIdx.x & 31;
  int xs = threadIdx.x >> 5;     // 0..7
  float2* dst = S6 + (size_t)blockIdx.x * 4096;
  for (int it = 0; it < 16; ++it) {
    int Xp = xs * 16 + it;
    float2 a = make_float2(0.f, 0.f);
#pragma unroll
    for (int l = 0; l < 32; ++l) cmadd(a, inb[l * 32 + j], tw[Xp * 32 + l]);
    dst[Xp * 32 + j] = a;
  }
}

// ---------------- inverse Y (irfft): S6 rows [32 modes] -> out rows [128 real] ----------------
// 64 rows per block; thread = Yp (128); per-thread mode coeffs cached in registers.
__global__ void __launch_bounds__(128) k_inv_y(const float2* __restrict__ S6,
                                               float* __restrict__ out,
                                               const float* __restrict__ twIYr,
                                               const float* __restrict__ twIYi) {
  __shared__ float2 rows[2048];  // 64 rows x 32 modes, 16KB
  const float2* src = S6 + (size_t)blockIdx.x * 2048;
  for (int i = threadIdx.x; i < 2048; i += 128) rows[i] = src[i];
  int Yp = threadIdx.x;
  float cr[32], ci[32];
#pragma unroll
  for (int jj = 0; jj < 32; ++jj) {
    cr[jj] = twIYr[jj * 128 + Yp];
    ci[jj] = twIYi[jj * 128 + Yp];
  }
  __syncthreads();
  float* dst = out + (size_t)blockIdx.x * 8192 + Yp;
  for (int r = 0; r < 64; ++r) {
    float a = 0.f;
#pragma unroll
    for (int jj = 0; jj < 32; ++jj) {
      float2 v = rows[r * 32 + jj];
      a = fmaf(v.x, cr[jj], fmaf(v.y, ci[jj], a));
    }
    dst[(size_t)r * 128] = a;
  }
}

extern "C" void kernel_launch(void* const* d_in, const int* in_sizes, int n_in,
                              void* d_out, int out_size, void* d_ws, size_t ws_size,
                              hipStream_t stream) {
  (void)in_sizes; (void)n_in; (void)out_size; (void)ws_size;
  const float* x  = (const float*)d_in[0];
  const float* wr = (const float*)d_in[1];
  const float* wi = (const float*)d_in[2];
  float* out = (float*)d_out;
  char* ws = (char*)d_ws;

  const float2* twFX  = (const float2*)(ws + OFF_TWFX);
  const float2* twFY  = (const float2*)(ws + OFF_TWFY);
  const float2* twFT  = (const float2*)(ws + OFF_TWFT);
  const float2* twIT  = (const float2*)(ws + OFF_TWIT);
  const float2* twIX  = (const float2*)(ws + OFF_TWIX);
  const float*  twIYr = (const float*)(ws + OFF_TWIYR);
  const float*  twIYi = (const float*)(ws + OFF_TWIYI);
  float2* S1 = (float2*)(ws + OFF_A);
  float2* S2 = (float2*)(ws + OFF_B);
  float2* S3 = (float2*)(ws + OFF_C);
  float2* S4 = (float2*)(ws + OFF_D);
  float2* S5 = (float2*)(ws + OFF_B);   // aliases S2 (dead)
  float2* S6 = (float2*)(ws + OFF_A);   // aliases S1 (dead)

  init_tables<<<dim3(80), dim3(256), 0, stream>>>(ws);
  k_fwd_x <<<dim3(2048), dim3(256), 0, stream>>>(x, S1, twFX);
  k_fwd_y <<<dim3(8192), dim3(256), 0, stream>>>(S1, S2, twFY);
  k_fwd_t <<<dim3(512),  dim3(256), 0, stream>>>(S2, S3, twFT);
  k_einsum<<<dim3(512),  dim3(256), 0, stream>>>(S3, wr, wi, S4);
  k_inv_t <<<dim3(512),  dim3(256), 0, stream>>>(S4, S5, twIT);
  k_inv_x <<<dim3(4096), dim3(256), 0, stream>>>(S5, S6, twIX);
  k_inv_y <<<dim3(8192), dim3(128), 0, stream>>>(S6, out, twIYr, twIYi);
}